// Round 7
// baseline (13424.695 us; speedup 1.0000x reference)
//
#include <hip/hip_runtime.h>
#include <cstdint>
#include <cstddef>

#define N_NODES 50000
#define N_EDGES 800000
#define F_IN_D 100
#define HDIM 128
#define CDIM 10

typedef unsigned short ushortT;

__device__ __forceinline__ float bf2f(unsigned int b16) {
  return __uint_as_float(b16 << 16);
}
__device__ __forceinline__ unsigned int f2bf(float f) {   // RNE bf16, returns low 16 bits
  unsigned int u = __float_as_uint(f);
  unsigned int r = u + 0x7FFFu + ((u >> 16) & 1u);
  return r >> 16;
}

// ---------------- preprocessing ----------------

__global__ void prep_convert_kernel(const int* __restrict__ ei, const float* __restrict__ ew,
                                    int* __restrict__ row32, int* __restrict__ col32,
                                    float* __restrict__ deg, int* __restrict__ cnt, int E) {
  bool is64 = true;
  for (int i = 0; i < 32; ++i) { if (ei[2 * i + 1] != 0) is64 = false; }
  int e = blockIdx.x * blockDim.x + threadIdx.x;
  if (e < E) {
    int r, c;
    if (is64) { r = ei[2 * e]; c = ei[2 * (E + e)]; }
    else      { r = ei[e];     c = ei[E + e]; }
    row32[e] = r;
    col32[e] = c;
    atomicAdd(&deg[c], ew[e]);
    atomicAdd(&cnt[c], 1);
  }
}

__global__ void prep_dis_kernel(const float* __restrict__ deg, float* __restrict__ dis, int n) {
  int i = blockIdx.x * blockDim.x + threadIdx.x;
  if (i < n) {
    float d = deg[i];
    dis[i] = d > 0.f ? rsqrtf(fmaxf(d, 1e-12f)) : 0.f;
  }
}

__global__ void prep_scanA_kernel(const int* __restrict__ cnt, int* __restrict__ partial, int n) {
  __shared__ int sd[256];
  int tid = threadIdx.x;
  int i = blockIdx.x * 256 + tid;
  sd[tid] = (i < n) ? cnt[i] : 0;
  __syncthreads();
  for (int s = 128; s > 0; s >>= 1) {
    if (tid < s) sd[tid] += sd[tid + s];
    __syncthreads();
  }
  if (tid == 0) partial[blockIdx.x] = sd[0];
}

__global__ void prep_scanB_kernel(int* __restrict__ partial, int* __restrict__ ptr, int nb, int n) {
  __shared__ int sd[256];
  int tid = threadIdx.x;
  int v = (tid < nb) ? partial[tid] : 0;
  sd[tid] = v;
  __syncthreads();
  for (int offd = 1; offd < 256; offd <<= 1) {
    int t = (tid >= offd) ? sd[tid - offd] : 0;
    __syncthreads();
    sd[tid] += t;
    __syncthreads();
  }
  if (tid < nb) partial[tid] = sd[tid] - v;
  if (tid == 255) ptr[n] = sd[255];
}

__global__ void prep_scanC_kernel(const int* __restrict__ cnt, const int* __restrict__ partial,
                                  int* __restrict__ ptr, int* __restrict__ pos, int n) {
  __shared__ int sd[256];
  int tid = threadIdx.x;
  int i = blockIdx.x * 256 + tid;
  int v = (i < n) ? cnt[i] : 0;
  sd[tid] = v;
  __syncthreads();
  for (int offd = 1; offd < 256; offd <<= 1) {
    int t = (tid >= offd) ? sd[tid - offd] : 0;
    __syncthreads();
    sd[tid] += t;
    __syncthreads();
  }
  if (i < n) {
    int p = partial[blockIdx.x] + sd[tid] - v;
    ptr[i] = p;
    pos[i] = p;
  }
}

__global__ void prep_place_kernel(const int* __restrict__ row32, const int* __restrict__ col32,
                                  const float* __restrict__ ew, const float* __restrict__ dis,
                                  int* __restrict__ pos, int* __restrict__ srcs,
                                  float* __restrict__ wsrt, int E) {
  int e = blockIdx.x * blockDim.x + threadIdx.x;
  if (e < E) {
    int r = row32[e], c = col32[e];
    int slot = atomicAdd(&pos[c], 1);
    srcs[slot] = r;
    wsrt[slot] = dis[r] * ew[e] * dis[c];
  }
}

// ---------------- propagation hop, d=128 bf16, fused y-add (+ optional ELU) ----------------
// One wave per node; lanes in 2 halves of 32; lane f4 covers 4 feats (uint2 = 4 bf16).
// sout[n][:] = maybeELU( y[n][:] + sum_j w_j * sin[src_j][:] ),  all rows bf16.
template <int TAG, bool ELU>
__global__ void hopb_kernel(const ushortT* __restrict__ sin_, const ushortT* __restrict__ y,
                            const int* __restrict__ ptr, const int* __restrict__ srcs,
                            const float* __restrict__ w, ushortT* __restrict__ sout, int n) {
  const int lane = threadIdx.x & 63;
  const int wid = threadIdx.x >> 6;        // 4 waves / 256-thread block
  const int half = lane >> 5;
  const int f4 = lane & 31;                // uint2 slot: 32 x 4 bf16 = 128 feats
  const int node = blockIdx.x * 4 + wid;
  if (node >= n) return;
  const uint2* s2 = (const uint2*)sin_;

  const int b = ptr[node], e = ptr[node + 1];
  const int len = e - b;
  const int c0 = (len + 1) >> 1;
  const int js = half ? (b + c0) : b;
  const int je = half ? e : (b + c0);

  float a0 = 0.f, a1 = 0.f, a2 = 0.f, a3 = 0.f;
  if (half == 0) {
    uint2 yv = ((const uint2*)y)[(size_t)node * 32 + f4];
    a0 = bf2f(yv.x & 0xFFFFu); a1 = bf2f(yv.x >> 16);
    a2 = bf2f(yv.y & 0xFFFFu); a3 = bf2f(yv.y >> 16);
  }

  int j = js;
  for (; j + 3 < je; j += 4) {
    int s0 = srcs[j], s1 = srcs[j + 1], s2i = srcs[j + 2], s3 = srcs[j + 3];
    float w0 = w[j], w1 = w[j + 1], w2 = w[j + 2], w3 = w[j + 3];
    uint2 v0 = s2[(size_t)s0 * 32 + f4];
    uint2 v1 = s2[(size_t)s1 * 32 + f4];
    uint2 v2 = s2[(size_t)s2i * 32 + f4];
    uint2 v3 = s2[(size_t)s3 * 32 + f4];
    a0 += w0 * bf2f(v0.x & 0xFFFFu) + w1 * bf2f(v1.x & 0xFFFFu) + w2 * bf2f(v2.x & 0xFFFFu) + w3 * bf2f(v3.x & 0xFFFFu);
    a1 += w0 * bf2f(v0.x >> 16)     + w1 * bf2f(v1.x >> 16)     + w2 * bf2f(v2.x >> 16)     + w3 * bf2f(v3.x >> 16);
    a2 += w0 * bf2f(v0.y & 0xFFFFu) + w1 * bf2f(v1.y & 0xFFFFu) + w2 * bf2f(v2.y & 0xFFFFu) + w3 * bf2f(v3.y & 0xFFFFu);
    a3 += w0 * bf2f(v0.y >> 16)     + w1 * bf2f(v1.y >> 16)     + w2 * bf2f(v2.y >> 16)     + w3 * bf2f(v3.y >> 16);
  }
  for (; j < je; ++j) {
    float w0 = w[j];
    uint2 v0 = s2[(size_t)srcs[j] * 32 + f4];
    a0 += w0 * bf2f(v0.x & 0xFFFFu);
    a1 += w0 * bf2f(v0.x >> 16);
    a2 += w0 * bf2f(v0.y & 0xFFFFu);
    a3 += w0 * bf2f(v0.y >> 16);
  }

  a0 += __shfl_xor(a0, 32);
  a1 += __shfl_xor(a1, 32);
  a2 += __shfl_xor(a2, 32);
  a3 += __shfl_xor(a3, 32);

  if (half == 0) {
    if (ELU) {
      a0 = a0 > 0.f ? a0 : expm1f(a0);
      a1 = a1 > 0.f ? a1 : expm1f(a1);
      a2 = a2 > 0.f ? a2 : expm1f(a2);
      a3 = a3 > 0.f ? a3 : expm1f(a3);
    }
    uint2 o;
    o.x = f2bf(a0) | (f2bf(a1) << 16);
    o.y = f2bf(a2) | (f2bf(a3) << 16);
    ((uint2*)sout)[(size_t)node * 32 + f4] = o;
  }
}

// d=10 hop, fp32: out[n][f] = ybuf[n*64+yOff+f] + sum_e w * z[s*zStride+zOff+f]
template <int TAG>
__global__ void hop10_kernel(const float* __restrict__ z, int zStride, int zOff,
                             const float* __restrict__ ybuf, int yOff,
                             const int* __restrict__ ptr, const int* __restrict__ srcs,
                             const float* __restrict__ wsrt, float* __restrict__ out, int n) {
  const int lane = threadIdx.x & 63;
  const int wid = threadIdx.x >> 6;
  const int sub = lane >> 4;
  const int f = lane & 15;
  const int node = blockIdx.x * 4 + wid;
  if (node >= n) return;

  const int b = ptr[node], e = ptr[node + 1];
  const int len = e - b;
  const int js = b + (len * sub) / 4;
  const int je = b + (len * (sub + 1)) / 4;

  float acc = 0.f;
  if (f < CDIM) {
    if (sub == 0) acc = ybuf[(size_t)node * 64 + yOff + f];
    int j = js;
    for (; j + 1 < je; j += 2) {
      int s0 = srcs[j], s1 = srcs[j + 1];
      float w0 = wsrt[j], w1 = wsrt[j + 1];
      acc += w0 * z[(size_t)s0 * zStride + zOff + f] + w1 * z[(size_t)s1 * zStride + zOff + f];
    }
    if (j < je) acc += wsrt[j] * z[(size_t)srcs[j] * zStride + zOff + f];
  }
  acc += __shfl_xor(acc, 16);
  acc += __shfl_xor(acc, 32);
  if (sub == 0 && f < CDIM) out[(size_t)node * CDIM + f] = acc;
}

// ---------------- dense GEMM ----------------
// out[n,c] = sum_k X[n,k]*B[k,c] (+bias).  64x64 tile, 256 threads, 4x4/thread.
// XBF: X rows are bf16.  OUTBF: write bf16 (packed uint2 per 4 cols).
// BMODE 0: B[k,c]=W[k*128+c].  BMODE 1: B[k,c]=W3[(c/10)*K*10 + k*10 + c%10] (c<60).
template <int TAG, int K_DIM, int BMODE, bool ADD_BIAS, bool XBF, bool OUTBF>
__global__ void gemm_kernel(const void* __restrict__ Xv, const float* __restrict__ W,
                            const float* __restrict__ bias, void* __restrict__ outv,
                            int n, int ostride) {
  __shared__ float xt[32][68];
  __shared__ float bt[32][64];
  const int tid = threadIdx.x;
  const int tx = tid & 15;
  const int ty = tid >> 4;
  const int n0 = blockIdx.x * 64;
  const int c0 = blockIdx.y * 64;
  float acc[4][4];
#pragma unroll
  for (int i = 0; i < 4; ++i)
#pragma unroll
    for (int j = 0; j < 4; ++j) acc[i][j] = 0.f;

  for (int k0 = 0; k0 < K_DIM; k0 += 32) {
#pragma unroll
    for (int i = 0; i < 8; ++i) {
      int idx = tid + i * 256;
      int nl = idx >> 5, kl = idx & 31;
      int nn = n0 + nl, kg = k0 + kl;
      float v = 0.f;
      if (nn < n && kg < K_DIM) {
        if (XBF) v = bf2f(((const ushortT*)Xv)[(size_t)nn * K_DIM + kg]);
        else     v = ((const float*)Xv)[(size_t)nn * K_DIM + kg];
      }
      xt[kl][nl] = v;
    }
#pragma unroll
    for (int i = 0; i < 8; ++i) {
      int idx = tid + i * 256;
      int kl = idx >> 6, cl = idx & 63;
      int kg = k0 + kl, c = c0 + cl;
      float v = 0.f;
      if (BMODE == 0) {
        if (kg < K_DIM) v = W[(size_t)kg * 128 + c];
      } else {
        if (kg < K_DIM && cl < 6 * CDIM)
          v = W[(size_t)(cl / CDIM) * (K_DIM * CDIM) + (size_t)kg * CDIM + (cl % CDIM)];
      }
      bt[kl][cl] = v;
    }
    __syncthreads();
#pragma unroll
    for (int kk = 0; kk < 32; ++kk) {
      float4 xv = *(const float4*)&xt[kk][tx * 4];
      float4 bv = *(const float4*)&bt[kk][ty * 4];
      acc[0][0] += xv.x * bv.x; acc[0][1] += xv.x * bv.y; acc[0][2] += xv.x * bv.z; acc[0][3] += xv.x * bv.w;
      acc[1][0] += xv.y * bv.x; acc[1][1] += xv.y * bv.y; acc[1][2] += xv.y * bv.z; acc[1][3] += xv.y * bv.w;
      acc[2][0] += xv.z * bv.x; acc[2][1] += xv.z * bv.y; acc[2][2] += xv.z * bv.z; acc[2][3] += xv.z * bv.w;
      acc[3][0] += xv.w * bv.x; acc[3][1] += xv.w * bv.y; acc[3][2] += xv.w * bv.z; acc[3][3] += xv.w * bv.w;
    }
    __syncthreads();
  }
#pragma unroll
  for (int i = 0; i < 4; ++i) {
    int nn = n0 + tx * 4 + i;
    if (nn >= n) continue;
#pragma unroll
    for (int j = 0; j < 4; ++j) {
      int c = c0 + ty * 4 + j;
      if (ADD_BIAS) {
        if (BMODE == 0) acc[i][j] += bias[c];
        else if (c < CDIM) acc[i][j] += bias[c];
      }
    }
    if (OUTBF) {
      uint2 o;
      o.x = f2bf(acc[i][0]) | (f2bf(acc[i][1]) << 16);
      o.y = f2bf(acc[i][2]) | (f2bf(acc[i][3]) << 16);
      *(uint2*)&((ushortT*)outv)[(size_t)nn * ostride + c0 + ty * 4] = o;
    } else {
#pragma unroll
      for (int j = 0; j < 4; ++j)
        ((float*)outv)[(size_t)nn * ostride + c0 + ty * 4 + j] = acc[i][j];
    }
  }
}

// ---------------- host ----------------

extern "C" void kernel_launch(void* const* d_in, const int* in_sizes, int n_in,
                              void* d_out, int out_size, void* d_ws, size_t ws_size,
                              hipStream_t stream) {
  const float* x  = (const float*)d_in[0];
  const int*   ei = (const int*)d_in[1];
  const float* ew = (const float*)d_in[2];
  const float* W1 = (const float*)d_in[3];
  const float* b1 = (const float*)d_in[4];
  const float* W2 = (const float*)d_in[5];
  const float* b2 = (const float*)d_in[6];
  const float* W3 = (const float*)d_in[7];
  const float* b3 = (const float*)d_in[8];
  float* out = (float*)d_out;

  const int N = N_NODES, E = N_EDGES;
  char* base = (char*)d_ws;
  size_t off = 0;
  auto alloc = [&](size_t bytes) -> char* {
    char* p = base + off;
    off += (bytes + 255) & ~(size_t)255;
    return p;
  };
  ushortT* S0 = (ushortT*)alloc((size_t)N * 128 * 2);   // 12.8 MB
  ushortT* S1 = (ushortT*)alloc((size_t)N * 128 * 2);
  ushortT* S2 = (ushortT*)alloc((size_t)N * 128 * 2);
  ushortT* Yb = (ushortT*)alloc((size_t)N * 128 * 2);
  float*  ybuf = (float*)alloc((size_t)N * 64 * 4);     // 12.8 MB (layer 3)
  float*  z0   = (float*)alloc((size_t)N * CDIM * 4);
  float*  z1   = (float*)alloc((size_t)N * CDIM * 4);
  int*    ptrA = (int*)alloc((size_t)(N + 1) * 4);
  int*    pos  = (int*)alloc((size_t)N * 4);
  int*    srcs = (int*)alloc((size_t)E * 4);
  float*  wsrt = (float*)alloc((size_t)E * 4);
  int*    part = (int*)alloc(256 * 4);

  // Preprocessing transients overlay ybuf (first written in layer 3).
  char* t = (char*)ybuf;
  int*   row32 = (int*)t;   t += (size_t)E * 4;
  int*   col32 = (int*)t;   t += (size_t)E * 4;
  float* deg   = (float*)t; t += (size_t)N * 4;
  float* dis   = (float*)t; t += (size_t)N * 4;
  int*   cnt   = (int*)t;   t += (size_t)N * 4;

  hipMemsetAsync(deg, 0, (size_t)N * 4, stream);
  hipMemsetAsync(cnt, 0, (size_t)N * 4, stream);

  const int eb = (E + 255) / 256;
  const int nb = (N + 255) / 256;
  prep_convert_kernel<<<eb, 256, 0, stream>>>(ei, ew, row32, col32, deg, cnt, E);
  prep_dis_kernel<<<nb, 256, 0, stream>>>(deg, dis, N);
  prep_scanA_kernel<<<nb, 256, 0, stream>>>(cnt, part, N);
  prep_scanB_kernel<<<1, 256, 0, stream>>>(part, ptrA, nb, N);
  prep_scanC_kernel<<<nb, 256, 0, stream>>>(cnt, part, ptrA, pos, N);
  prep_place_kernel<<<eb, 256, 0, stream>>>(row32, col32, ew, dis, pos, srcs, wsrt, E);

  const dim3 gemmGrid((N + 63) / 64, 2);
  const int hopBlocks = (N + 3) / 4;

  // ===== layer 1: in = x (fp32, K=100) -> h1 bf16 in S2.  Horner with JIT y. =====
  {
    ushortT* Y = Yb; ushortT* P = S1; ushortT* Q = S2;
    gemm_kernel<15, F_IN_D, 0, false, false, true><<<gemmGrid, 256, 0, stream>>>(x, W1 + (size_t)5 * F_IN_D * 128, b1, P, N, 128);
    gemm_kernel<14, F_IN_D, 0, false, false, true><<<gemmGrid, 256, 0, stream>>>(x, W1 + (size_t)4 * F_IN_D * 128, b1, Y, N, 128);
    hopb_kernel<14, false><<<hopBlocks, 256, 0, stream>>>(P, Y, ptrA, srcs, wsrt, Q, N);
    { ushortT* tmp = P; P = Q; Q = tmp; }
    gemm_kernel<13, F_IN_D, 0, false, false, true><<<gemmGrid, 256, 0, stream>>>(x, W1 + (size_t)3 * F_IN_D * 128, b1, Y, N, 128);
    hopb_kernel<13, false><<<hopBlocks, 256, 0, stream>>>(P, Y, ptrA, srcs, wsrt, Q, N);
    { ushortT* tmp = P; P = Q; Q = tmp; }
    gemm_kernel<12, F_IN_D, 0, false, false, true><<<gemmGrid, 256, 0, stream>>>(x, W1 + (size_t)2 * F_IN_D * 128, b1, Y, N, 128);
    hopb_kernel<12, false><<<hopBlocks, 256, 0, stream>>>(P, Y, ptrA, srcs, wsrt, Q, N);
    { ushortT* tmp = P; P = Q; Q = tmp; }
    gemm_kernel<11, F_IN_D, 0, false, false, true><<<gemmGrid, 256, 0, stream>>>(x, W1 + (size_t)1 * F_IN_D * 128, b1, Y, N, 128);
    hopb_kernel<11, false><<<hopBlocks, 256, 0, stream>>>(P, Y, ptrA, srcs, wsrt, Q, N);
    { ushortT* tmp = P; P = Q; Q = tmp; }
    gemm_kernel<10, F_IN_D, 0, true, false, true><<<gemmGrid, 256, 0, stream>>>(x, W1, b1, Y, N, 128);
    hopb_kernel<10, true><<<hopBlocks, 256, 0, stream>>>(P, Y, ptrA, srcs, wsrt, Q, N);
    // h1 in S2
  }

  // ===== layer 2: in = S2 (bf16, K=128) -> h2 bf16 in S1 =====
  {
    const ushortT* in = S2;
    ushortT* Y = Yb; ushortT* P = S0; ushortT* Q = S1;
    gemm_kernel<25, HDIM, 0, false, true, true><<<gemmGrid, 256, 0, stream>>>(in, W2 + (size_t)5 * HDIM * 128, b2, P, N, 128);
    gemm_kernel<24, HDIM, 0, false, true, true><<<gemmGrid, 256, 0, stream>>>(in, W2 + (size_t)4 * HDIM * 128, b2, Y, N, 128);
    hopb_kernel<24, false><<<hopBlocks, 256, 0, stream>>>(P, Y, ptrA, srcs, wsrt, Q, N);
    { ushortT* tmp = P; P = Q; Q = tmp; }
    gemm_kernel<23, HDIM, 0, false, true, true><<<gemmGrid, 256, 0, stream>>>(in, W2 + (size_t)3 * HDIM * 128, b2, Y, N, 128);
    hopb_kernel<23, false><<<hopBlocks, 256, 0, stream>>>(P, Y, ptrA, srcs, wsrt, Q, N);
    { ushortT* tmp = P; P = Q; Q = tmp; }
    gemm_kernel<22, HDIM, 0, false, true, true><<<gemmGrid, 256, 0, stream>>>(in, W2 + (size_t)2 * HDIM * 128, b2, Y, N, 128);
    hopb_kernel<22, false><<<hopBlocks, 256, 0, stream>>>(P, Y, ptrA, srcs, wsrt, Q, N);
    { ushortT* tmp = P; P = Q; Q = tmp; }
    gemm_kernel<21, HDIM, 0, false, true, true><<<gemmGrid, 256, 0, stream>>>(in, W2 + (size_t)1 * HDIM * 128, b2, Y, N, 128);
    hopb_kernel<21, false><<<hopBlocks, 256, 0, stream>>>(P, Y, ptrA, srcs, wsrt, Q, N);
    { ushortT* tmp = P; P = Q; Q = tmp; }
    gemm_kernel<20, HDIM, 0, true, true, true><<<gemmGrid, 256, 0, stream>>>(in, W2, b2, Y, N, 128);
    hopb_kernel<20, true><<<hopBlocks, 256, 0, stream>>>(P, Y, ptrA, srcs, wsrt, Q, N);
    // h2 in S1
  }

  // ===== layer 3: in = S1 (bf16) -> out fp32 via Horner on projected y (BMODE1) =====
  {
    dim3 g3((N + 63) / 64, 1);
    gemm_kernel<30, HDIM, 1, true, true, false><<<g3, 256, 0, stream>>>(S1, W3, b3, ybuf, N, 64);
    hop10_kernel<35><<<hopBlocks, 256, 0, stream>>>(ybuf, 64, 50, ybuf, 40, ptrA, srcs, wsrt, z0, N);
    hop10_kernel<34><<<hopBlocks, 256, 0, stream>>>(z0, 10, 0, ybuf, 30, ptrA, srcs, wsrt, z1, N);
    hop10_kernel<33><<<hopBlocks, 256, 0, stream>>>(z1, 10, 0, ybuf, 20, ptrA, srcs, wsrt, z0, N);
    hop10_kernel<32><<<hopBlocks, 256, 0, stream>>>(z0, 10, 0, ybuf, 10, ptrA, srcs, wsrt, z1, N);
    hop10_kernel<31><<<hopBlocks, 256, 0, stream>>>(z1, 10, 0, ybuf, 0, ptrA, srcs, wsrt, out, N);
  }

  (void)in_sizes; (void)n_in; (void)out_size; (void)ws_size;
}